// Round 1
// baseline (726.928 us; speedup 1.0000x reference)
//
#include <hip/hip_runtime.h>
#include <hip/hip_bf16.h>
#include <math.h>

// Problem constants
#define NTOK  4096      // B*T
#define CDIM  1024
#define HDIM  4096
#define NEXP  8
#define TOPK  2

using short8 = __attribute__((ext_vector_type(8))) short;
using f32x4  = __attribute__((ext_vector_type(4))) float;

__device__ inline ushort f2bf(float f) {
    uint32_t u = __builtin_bit_cast(uint32_t, f);
    uint32_t r = (u + 0x7FFFu + ((u >> 16) & 1u)) >> 16;
    return (ushort)r;
}

// ---------------------------------------------------------------------------
// Gate: one wave per token. fp32 logits, top-2, normalized weights.
// Also converts x to bf16.
__global__ __launch_bounds__(256)
void gate_kernel(const float* __restrict__ x, const float* __restrict__ Wg,
                 const float* __restrict__ bg, int* __restrict__ counts,
                 int* __restrict__ tlist, float* __restrict__ wslot,
                 ushort* __restrict__ xbf) {
    int wave = threadIdx.x >> 6, lane = threadIdx.x & 63;
    int t = blockIdx.x * 4 + wave;
    const float* xr = x + (size_t)t * CDIM;

    float acc[NEXP];
#pragma unroll
    for (int e = 0; e < NEXP; e++) acc[e] = 0.f;

#pragma unroll
    for (int i = 0; i < CDIM / 64; i++) {
        int c = lane + 64 * i;
        float xv = xr[c];
        xbf[(size_t)t * CDIM + c] = f2bf(xv);
        const float* wr = Wg + (size_t)c * NEXP;
#pragma unroll
        for (int e = 0; e < NEXP; e++) acc[e] += xv * wr[e];
    }
#pragma unroll
    for (int e = 0; e < NEXP; e++) {
        float v = acc[e];
        for (int off = 32; off > 0; off >>= 1) v += __shfl_xor(v, off);
        acc[e] = v + bg[e];
    }
    if (lane == 0) {
        int i1 = 0; float m1 = acc[0];
#pragma unroll
        for (int e = 1; e < NEXP; e++) if (acc[e] > m1) { m1 = acc[e]; i1 = e; }
        int i2 = -1; float m2 = -1e30f;
#pragma unroll
        for (int e = 0; e < NEXP; e++) if (e != i1 && acc[e] > m2) { m2 = acc[e]; i2 = e; }
        // softmax top-2 renormalized: w0 = g1/(g1+g2) = 1/(1+exp(l2-l1))
        float w0 = 1.f / (1.f + expf(m2 - m1));
        float w1 = 1.f - w0;
        int p0 = atomicAdd(&counts[i1], 1);
        tlist[i1 * NTOK + p0] = t * 2;
        int p1 = atomicAdd(&counts[i2], 1);
        tlist[i2 * NTOK + p1] = t * 2 + 1;
        wslot[t * 2]     = w0;
        wslot[t * 2 + 1] = w1;
    }
}

// ---------------------------------------------------------------------------
// Transpose + fp32->bf16: in [E][R][Ccols] f32  ->  out [E][Ccols][R] bf16
// grid (Ccols/32, R/32, E), block (32, 8)
__global__ __launch_bounds__(256)
void transpose_kernel(const float* __restrict__ in, ushort* __restrict__ out,
                      int R, int Ccols) {
    __shared__ float tile[32][33];
    int e = blockIdx.z;
    const float* src = in + (size_t)e * R * Ccols;
    ushort* dst = out + (size_t)e * Ccols * R;
    int c0 = blockIdx.x * 32, r0 = blockIdx.y * 32;
    int tx = threadIdx.x, ty = threadIdx.y;
#pragma unroll
    for (int j = 0; j < 4; j++)
        tile[ty + 8 * j][tx] = src[(size_t)(r0 + ty + 8 * j) * Ccols + c0 + tx];
    __syncthreads();
#pragma unroll
    for (int j = 0; j < 4; j++)
        dst[(size_t)(c0 + ty + 8 * j) * R + r0 + tx] = f2bf(tile[tx][ty + 8 * j]);
}

// ---------------------------------------------------------------------------
// Sparse-expert GEMM: rows gathered by per-expert token list.
//   A  : bf16 [*, K], row index = tlist_value >> ashift
//   Bt : bf16 [E][N][K] (pre-transposed so rows are K-consecutive)
//   Out: row index = tlist_value; bf16 (h) or f32 (y)
// 128x128 tile, BK=32, 4 waves x (64x64), v_mfma_f32_16x16x32_bf16.
template<int GELU, int OUTBF16>
__global__ __launch_bounds__(256)
void moe_gemm(const ushort* __restrict__ A, const ushort* __restrict__ Bt,
              const float* __restrict__ bias, const int* __restrict__ tlist,
              const int* __restrict__ counts, void* __restrict__ Out,
              int K, int N, int ashift) {
    int e = blockIdx.z;
    int cnt = counts[e];
    int m0 = blockIdx.y * 128;
    if (m0 >= cnt) return;
    int n0 = blockIdx.x * 128;

    __shared__ ushort As[128 * 40];   // padded pitch 40 (80B) to spread banks
    __shared__ ushort Bs[128 * 40];
    __shared__ int rowv[128];

    int tid = threadIdx.x;
    if (tid < 128) {
        int r = m0 + tid;
        rowv[tid] = tlist[e * NTOK + (r < cnt ? r : cnt - 1)];
    }
    __syncthreads();

    const ushort* Be = Bt + (size_t)e * N * K;

    f32x4 acc[4][4] = {};

    int lane = tid & 63, w = tid >> 6;
    int wm = (w >> 1) * 64, wn = (w & 1) * 64;
    int quad = lane >> 4, l16 = lane & 15;

    int srow = tid >> 2;            // 0..63
    int scol = (tid & 3) * 8;       // bf16 elem offset {0,8,16,24}

    for (int kt = 0; kt < K; kt += 32) {
#pragma unroll
        for (int s = 0; s < 2; s++) {
            int row = srow + s * 64;
            const ushort* ap = A + (size_t)(rowv[row] >> ashift) * K + kt + scol;
            *(int4*)&As[row * 40 + scol] = *(const int4*)ap;
            const ushort* bp = Be + (size_t)(n0 + row) * K + kt + scol;
            *(int4*)&Bs[row * 40 + scol] = *(const int4*)bp;
        }
        __syncthreads();

        short8 a[4], b[4];
#pragma unroll
        for (int mt = 0; mt < 4; mt++)
            a[mt] = *(short8*)&As[(wm + mt * 16 + l16) * 40 + quad * 8];
#pragma unroll
        for (int nt = 0; nt < 4; nt++)
            b[nt] = *(short8*)&Bs[(wn + nt * 16 + l16) * 40 + quad * 8];
#pragma unroll
        for (int mt = 0; mt < 4; mt++)
#pragma unroll
            for (int nt = 0; nt < 4; nt++)
                acc[mt][nt] = __builtin_amdgcn_mfma_f32_16x16x32_bf16(
                    a[mt], b[nt], acc[mt][nt], 0, 0, 0);
        __syncthreads();
    }

    // Epilogue. C/D layout: col = lane&15, row = (lane>>4)*4 + reg.
    float* outF = (float*)Out;
    ushort* outH = (ushort*)Out;
    const float* be = bias + (size_t)e * N;
#pragma unroll
    for (int mt = 0; mt < 4; mt++) {
#pragma unroll
        for (int r = 0; r < 4; r++) {
            int lrow = wm + mt * 16 + quad * 4 + r;
            if (m0 + lrow < cnt) {
                int v = rowv[lrow];
                size_t base = (size_t)v * N;
#pragma unroll
                for (int nt = 0; nt < 4; nt++) {
                    int col = n0 + wn + nt * 16 + l16;
                    float val = acc[mt][nt][r] + be[col];
                    if (GELU) val = 0.5f * val * (1.0f + erff(val * 0.70710678118654752f));
                    if (OUTBF16) outH[base + col] = f2bf(val);
                    else         outF[base + col] = val;
                }
            }
        }
    }
}

// ---------------------------------------------------------------------------
// out[t] = w0 * y[2t] + w1 * y[2t+1]   (fully coalesced, writes every element)
__global__ __launch_bounds__(256)
void combine_kernel(const float* __restrict__ y, const float* __restrict__ wslot,
                    float* __restrict__ out) {
    int idx = blockIdx.x * 256 + threadIdx.x;     // one float4 each
    int c4 = idx & (CDIM / 4 - 1);
    int t = idx >> 8;                              // CDIM/4 == 256
    float w0 = wslot[2 * t], w1 = wslot[2 * t + 1];
    const float4* y0 = (const float4*)(y + (size_t)(2 * t) * CDIM);
    const float4* y1 = (const float4*)(y + (size_t)(2 * t + 1) * CDIM);
    float4 a = y0[c4], b = y1[c4], o;
    o.x = w0 * a.x + w1 * b.x;
    o.y = w0 * a.y + w1 * b.y;
    o.z = w0 * a.z + w1 * b.z;
    o.w = w0 * a.w + w1 * b.w;
    ((float4*)(out + (size_t)t * CDIM))[c4] = o;
}

// ---------------------------------------------------------------------------
extern "C" void kernel_launch(void* const* d_in, const int* in_sizes, int n_in,
                              void* d_out, int out_size, void* d_ws, size_t ws_size,
                              hipStream_t stream) {
    const float* x  = (const float*)d_in[0];
    const float* Wg = (const float*)d_in[1];
    const float* bg = (const float*)d_in[2];
    const float* W1 = (const float*)d_in[3];
    const float* b1 = (const float*)d_in[4];
    const float* W2 = (const float*)d_in[5];
    const float* b2 = (const float*)d_in[6];
    float* out = (float*)d_out;
    char* ws = (char*)d_ws;

    // workspace layout (bytes)
    size_t off = 0;
    int*    counts = (int*)(ws + off);    off += 256;
    int*    tlist  = (int*)(ws + off);    off += (size_t)NEXP * NTOK * 4;        // 128 KB
    float*  wslot  = (float*)(ws + off);  off += (size_t)NTOK * TOPK * 4;        // 32 KB
    ushort* xbf    = (ushort*)(ws + off); off += (size_t)NTOK * CDIM * 2;        // 8 MB
    ushort* WT     = (ushort*)(ws + off); off += (size_t)NEXP * CDIM * HDIM * 2; // 64 MB (shared W1T/W2T)
    ushort* h      = (ushort*)(ws + off); off += (size_t)NTOK * TOPK * HDIM * 2; // 64 MB
    float*  y      = (float*)(ws + off);  off += (size_t)NTOK * TOPK * CDIM * 4; // 32 MB

    hipMemsetAsync(counts, 0, NEXP * sizeof(int), stream);

    gate_kernel<<<NTOK / 4, 256, 0, stream>>>(x, Wg, bg, counts, tlist, wslot, xbf);

    // W1 [E][C][H] -> WT [E][H][C] bf16
    transpose_kernel<<<dim3(HDIM / 32, CDIM / 32, NEXP), dim3(32, 8), 0, stream>>>(
        W1, WT, CDIM, HDIM);

    // h[slot] = gelu(x @ W1 + b1), bf16
    moe_gemm<1, 1><<<dim3(HDIM / 128, NTOK / 128, NEXP), 256, 0, stream>>>(
        xbf, WT, b1, tlist, counts, (void*)h, CDIM, HDIM, 1);

    // W2 [E][H][C] -> WT [E][C][H] bf16  (reuses WT buffer)
    transpose_kernel<<<dim3(CDIM / 32, HDIM / 32, NEXP), dim3(32, 8), 0, stream>>>(
        W2, WT, HDIM, CDIM);

    // y[slot] = h @ W2 + b2, f32
    moe_gemm<0, 0><<<dim3(CDIM / 128, NTOK / 128, NEXP), 256, 0, stream>>>(
        h, WT, b2, tlist, counts, (void*)y, HDIM, CDIM, 0);

    combine_kernel<<<(NTOK * CDIM / 4) / 256, 256, 0, stream>>>(y, wslot, out);
}

// Round 2
// 701.747 us; speedup vs baseline: 1.0359x; 1.0359x over previous
//
#include <hip/hip_runtime.h>
#include <hip/hip_bf16.h>
#include <math.h>

// Problem constants
#define NTOK  4096      // B*T
#define CDIM  1024
#define HDIM  4096
#define NEXP  8
#define TOPK  2

using short8 = __attribute__((ext_vector_type(8))) short;
using f32x4  = __attribute__((ext_vector_type(4))) float;
using us4    = __attribute__((ext_vector_type(4))) unsigned short;

__device__ inline ushort f2bf(float f) {
    uint32_t u = __builtin_bit_cast(uint32_t, f);
    uint32_t r = (u + 0x7FFFu + ((u >> 16) & 1u)) >> 16;
    return (ushort)r;
}

// async global->LDS, 16 B per lane; LDS dest = wave-uniform base + lane*16
__device__ __forceinline__ void gl_lds16(const void* g, void* l) {
    __builtin_amdgcn_global_load_lds(
        (const __attribute__((address_space(1))) void*)(void*)g,
        (__attribute__((address_space(3))) void*)l, 16, 0, 0);
}

// ---------------------------------------------------------------------------
// Gate: one wave per token. fp32 logits, top-2, normalized weights.
// Also converts x to bf16.
__global__ __launch_bounds__(256)
void gate_kernel(const float* __restrict__ x, const float* __restrict__ Wg,
                 const float* __restrict__ bg, int* __restrict__ counts,
                 int* __restrict__ tlist, float* __restrict__ wslot,
                 ushort* __restrict__ xbf) {
    int wave = threadIdx.x >> 6, lane = threadIdx.x & 63;
    int t = blockIdx.x * 4 + wave;
    const float* xr = x + (size_t)t * CDIM;

    float acc[NEXP];
#pragma unroll
    for (int e = 0; e < NEXP; e++) acc[e] = 0.f;

#pragma unroll
    for (int i = 0; i < CDIM / 64; i++) {
        int c = lane + 64 * i;
        float xv = xr[c];
        xbf[(size_t)t * CDIM + c] = f2bf(xv);
        const float* wr = Wg + (size_t)c * NEXP;
#pragma unroll
        for (int e = 0; e < NEXP; e++) acc[e] += xv * wr[e];
    }
#pragma unroll
    for (int e = 0; e < NEXP; e++) {
        float v = acc[e];
        for (int off = 32; off > 0; off >>= 1) v += __shfl_xor(v, off);
        acc[e] = v + bg[e];
    }
    if (lane == 0) {
        int i1 = 0; float m1 = acc[0];
#pragma unroll
        for (int e = 1; e < NEXP; e++) if (acc[e] > m1) { m1 = acc[e]; i1 = e; }
        int i2 = -1; float m2 = -1e30f;
#pragma unroll
        for (int e = 0; e < NEXP; e++) if (e != i1 && acc[e] > m2) { m2 = acc[e]; i2 = e; }
        // softmax top-2 renormalized: w0 = g1/(g1+g2) = 1/(1+exp(l2-l1))
        float w0 = 1.f / (1.f + expf(m2 - m1));
        float w1 = 1.f - w0;
        int p0 = atomicAdd(&counts[i1], 1);
        tlist[i1 * NTOK + p0] = t * 2;
        int p1 = atomicAdd(&counts[i2], 1);
        tlist[i2 * NTOK + p1] = t * 2 + 1;
        wslot[t * 2]     = w0;
        wslot[t * 2 + 1] = w1;
    }
}

// ---------------------------------------------------------------------------
// Transpose + fp32->bf16: in [E][R][Ccols] f32 -> out [E][Ccols][R] bf16
// 64x64 tiles, 256 threads. float4 global loads, ushort4 (8B) global stores.
// grid (Ccols/64, R/64, E)
__global__ __launch_bounds__(256)
void transpose_kernel(const float* __restrict__ in, ushort* __restrict__ out,
                      int R, int Ccols) {
    __shared__ float tile[64][68];   // pitch 68: float4-aligned, bank-benign
    int e = blockIdx.z;
    const float* src = in + (size_t)e * R * Ccols;
    ushort* dst = out + (size_t)e * Ccols * R;
    int c0 = blockIdx.x * 64, r0 = blockIdx.y * 64;
    int tid = threadIdx.x;
    int tx = tid & 15, ty = tid >> 4;
#pragma unroll
    for (int j = 0; j < 4; j++) {
        float4 v = *(const float4*)&src[(size_t)(r0 + ty + 16 * j) * Ccols + c0 + tx * 4];
        *(float4*)&tile[ty + 16 * j][tx * 4] = v;
    }
    __syncthreads();
#pragma unroll
    for (int j = 0; j < 4; j++) {
        int c = ty + 16 * j;
        us4 o;
#pragma unroll
        for (int i = 0; i < 4; i++) o[i] = f2bf(tile[tx * 4 + i][c]);
        *(us4*)&dst[(size_t)(c0 + c) * R + r0 + tx * 4] = o;
    }
}

// ---------------------------------------------------------------------------
// Sparse-expert GEMM: rows gathered by per-expert token list.
//   A  : bf16 [*, K], row index = tlist_value >> ashift
//   Bt : bf16 [E][N][K] (pre-transposed so rows are K-consecutive)
//   Out: row index = tlist_value; bf16 (h) or f32 (y)
// 128x128 tile, BK=32, 4 waves x (64x64), v_mfma_f32_16x16x32_bf16.
// Staging via global_load_lds width=16 (m97 structure). LDS pitch 32 unpadded
// (bank conflicts measured at 0.016% of cycles — padding not worth losing
// the contiguous lane order global_load_lds requires).
template<int GELU, int OUTBF16>
__global__ __launch_bounds__(256)
void moe_gemm(const ushort* __restrict__ A, const ushort* __restrict__ Bt,
              const float* __restrict__ bias, const int* __restrict__ tlist,
              const int* __restrict__ counts, void* __restrict__ Out,
              int K, int N, int ashift) {
    int e = blockIdx.z;
    int cnt = counts[e];
    int m0 = blockIdx.y * 128;
    if (m0 >= cnt) return;
    int n0 = blockIdx.x * 128;

    __shared__ ushort As[128 * 32];
    __shared__ ushort Bs[128 * 32];
    __shared__ int rowv[128];

    int tid = threadIdx.x;
    if (tid < 128) {
        int r = m0 + tid;
        rowv[tid] = tlist[e * NTOK + (r < cnt ? r : cnt - 1)];
    }
    __syncthreads();

    const ushort* Be = Bt + (size_t)e * N * K;

    f32x4 acc[4][4] = {};

    int lane = tid & 63, w = tid >> 6;
    int wm = (w >> 1) * 64, wn = (w & 1) * 64;
    int quad = lane >> 4, l16 = lane & 15;

    int srow = tid >> 2;            // 0..63 ; wave w covers rows [w*16, w*16+16)
    int scol = (tid & 3) * 8;       // bf16 elem offset {0,8,16,24}

    for (int kt = 0; kt < K; kt += 32) {
#pragma unroll
        for (int s = 0; s < 2; s++) {
            int row = srow + s * 64;
            const ushort* ap = A + (size_t)(rowv[row] >> ashift) * K + kt + scol;
            gl_lds16(ap, &As[(w * 16 + s * 64) * 32]);
            const ushort* bp = Be + (size_t)(n0 + row) * K + kt + scol;
            gl_lds16(bp, &Bs[(w * 16 + s * 64) * 32]);
        }
        __syncthreads();

        short8 a[4], b[4];
#pragma unroll
        for (int mt = 0; mt < 4; mt++)
            a[mt] = *(short8*)&As[(wm + mt * 16 + l16) * 32 + quad * 8];
#pragma unroll
        for (int nt = 0; nt < 4; nt++)
            b[nt] = *(short8*)&Bs[(wn + nt * 16 + l16) * 32 + quad * 8];
#pragma unroll
        for (int mt = 0; mt < 4; mt++)
#pragma unroll
            for (int nt = 0; nt < 4; nt++)
                acc[mt][nt] = __builtin_amdgcn_mfma_f32_16x16x32_bf16(
                    a[mt], b[nt], acc[mt][nt], 0, 0, 0);
        __syncthreads();
    }

    // Epilogue. C/D layout: col = lane&15, row = (lane>>4)*4 + reg.
    float* outF = (float*)Out;
    ushort* outH = (ushort*)Out;
    const float* be = bias + (size_t)e * N;
#pragma unroll
    for (int mt = 0; mt < 4; mt++) {
#pragma unroll
        for (int r = 0; r < 4; r++) {
            int lrow = wm + mt * 16 + quad * 4 + r;
            if (m0 + lrow < cnt) {
                int v = rowv[lrow];
                size_t base = (size_t)v * N;
#pragma unroll
                for (int nt = 0; nt < 4; nt++) {
                    int col = n0 + wn + nt * 16 + l16;
                    float val = acc[mt][nt][r] + be[col];
                    if (GELU) val = 0.5f * val * (1.0f + erff(val * 0.70710678118654752f));
                    if (OUTBF16) outH[base + col] = f2bf(val);
                    else         outF[base + col] = val;
                }
            }
        }
    }
}

// ---------------------------------------------------------------------------
// out[t] = w0 * y[2t] + w1 * y[2t+1]   (fully coalesced, writes every element)
__global__ __launch_bounds__(256)
void combine_kernel(const float* __restrict__ y, const float* __restrict__ wslot,
                    float* __restrict__ out) {
    int idx = blockIdx.x * 256 + threadIdx.x;     // one float4 each
    int c4 = idx & (CDIM / 4 - 1);
    int t = idx >> 8;                              // CDIM/4 == 256
    float w0 = wslot[2 * t], w1 = wslot[2 * t + 1];
    const float4* y0 = (const float4*)(y + (size_t)(2 * t) * CDIM);
    const float4* y1 = (const float4*)(y + (size_t)(2 * t + 1) * CDIM);
    float4 a = y0[c4], b = y1[c4], o;
    o.x = w0 * a.x + w1 * b.x;
    o.y = w0 * a.y + w1 * b.y;
    o.z = w0 * a.z + w1 * b.z;
    o.w = w0 * a.w + w1 * b.w;
    ((float4*)(out + (size_t)t * CDIM))[c4] = o;
}

// ---------------------------------------------------------------------------
extern "C" void kernel_launch(void* const* d_in, const int* in_sizes, int n_in,
                              void* d_out, int out_size, void* d_ws, size_t ws_size,
                              hipStream_t stream) {
    const float* x  = (const float*)d_in[0];
    const float* Wg = (const float*)d_in[1];
    const float* bg = (const float*)d_in[2];
    const float* W1 = (const float*)d_in[3];
    const float* b1 = (const float*)d_in[4];
    const float* W2 = (const float*)d_in[5];
    const float* b2 = (const float*)d_in[6];
    float* out = (float*)d_out;
    char* ws = (char*)d_ws;

    // workspace layout (bytes)
    size_t off = 0;
    int*    counts = (int*)(ws + off);    off += 256;
    int*    tlist  = (int*)(ws + off);    off += (size_t)NEXP * NTOK * 4;        // 128 KB
    float*  wslot  = (float*)(ws + off);  off += (size_t)NTOK * TOPK * 4;        // 32 KB
    ushort* xbf    = (ushort*)(ws + off); off += (size_t)NTOK * CDIM * 2;        // 8 MB
    ushort* WT     = (ushort*)(ws + off); off += (size_t)NEXP * CDIM * HDIM * 2; // 64 MB (shared W1T/W2T)
    ushort* h      = (ushort*)(ws + off); off += (size_t)NTOK * TOPK * HDIM * 2; // 64 MB
    float*  y      = (float*)(ws + off);  off += (size_t)NTOK * TOPK * CDIM * 4; // 32 MB

    hipMemsetAsync(counts, 0, NEXP * sizeof(int), stream);

    gate_kernel<<<NTOK / 4, 256, 0, stream>>>(x, Wg, bg, counts, tlist, wslot, xbf);

    // W1 [E][C][H] -> WT [E][H][C] bf16
    transpose_kernel<<<dim3(HDIM / 64, CDIM / 64, NEXP), 256, 0, stream>>>(
        W1, WT, CDIM, HDIM);

    // h[slot] = gelu(x @ W1 + b1), bf16
    moe_gemm<1, 1><<<dim3(HDIM / 128, NTOK / 128, NEXP), 256, 0, stream>>>(
        xbf, WT, b1, tlist, counts, (void*)h, CDIM, HDIM, 1);

    // W2 [E][H][C] -> WT [E][C][H] bf16  (reuses WT buffer; stream-ordered
    // after GEMM1 so the overwrite is safe)
    transpose_kernel<<<dim3(CDIM / 64, HDIM / 64, NEXP), 256, 0, stream>>>(
        W2, WT, HDIM, CDIM);

    // y[slot] = h @ W2 + b2, f32
    moe_gemm<0, 0><<<dim3(CDIM / 128, NTOK / 128, NEXP), 256, 0, stream>>>(
        h, WT, b2, tlist, counts, (void*)y, HDIM, CDIM, 0);

    combine_kernel<<<(NTOK * CDIM / 4) / 256, 256, 0, stream>>>(y, wslot, out);
}